// Round 3
// baseline (318.789 us; speedup 1.0000x reference)
//
#include <hip/hip_runtime.h>

#define S_LEN  2048
#define DMODEL 1024
#define NHEAD  16
#define DHEAD  64
#define SCALE_F 0.125f

typedef unsigned short ushort_t;
typedef __attribute__((ext_vector_type(8))) short bf16x8;
typedef __attribute__((ext_vector_type(4))) float f32x4;

typedef __attribute__((address_space(1))) void gv_t;
typedef __attribute__((address_space(3))) void lv_t;

__device__ __forceinline__ ushort_t f2bf(float f) {
    unsigned u = __builtin_bit_cast(unsigned, f);
    unsigned r = (u + 0x7FFFu + ((u >> 16) & 1u)) >> 16;
    return (ushort_t)r;
}

__device__ __forceinline__ void gload16(const ushort_t* g, ushort_t* l) {
    __builtin_amdgcn_global_load_lds((gv_t*)g, (lv_t*)l, 16, 0, 0);
}

// Cast x, Wq, Wk, Wv, Wo (f32) into one contiguous bf16 region:
// [xb (4096x1024) | Wqkv (3072x1024) | Wo (1024x1024)]
__global__ void cast_all(const float* __restrict__ x,
                         const float* __restrict__ Wq, const float* __restrict__ Wk,
                         const float* __restrict__ Wv, const float* __restrict__ Wo,
                         ushort_t* __restrict__ dst, int n4) {
    int i = blockIdx.x * blockDim.x + threadIdx.x;
    int stride = gridDim.x * blockDim.x;
    for (int idx = i; idx < n4; idx += stride) {
        const float* src; int off;
        if (idx < 1048576)      { src = x;  off = idx; }
        else if (idx < 1310720) { src = Wq; off = idx - 1048576; }
        else if (idx < 1572864) { src = Wk; off = idx - 1310720; }
        else if (idx < 1835008) { src = Wv; off = idx - 1572864; }
        else                    { src = Wo; off = idx - 1835008; }
        float4 f = ((const float4*)src)[off];
        ushort4 o;
        o.x = f2bf(f.x); o.y = f2bf(f.y); o.z = f2bf(f.z); o.w = f2bf(f.w);
        ((ushort4*)dst)[idx] = o;
    }
}

// C = A @ B^T + bias.  A: [M][K] bf16, Bw: [N][K] bf16 (row-major, K-contig).
// MODE 0 (BM=128): fused QKV epilogue, N=3072: mat=col>>10 selects Q/K/V dest.
// MODE 2 (BM=64): out0 = f32 flat [M][N].
template<int MODE, int BM>
__launch_bounds__(256)
__global__ void gemm_bt(const ushort_t* __restrict__ A, const ushort_t* __restrict__ Bw,
                        const float* __restrict__ b0, const float* __restrict__ b1,
                        const float* __restrict__ b2,
                        void* __restrict__ out0, void* __restrict__ out1, void* __restrict__ out2,
                        int M, int N, int K) {
    constexpr int MF = BM / 32;
    __shared__ ushort_t As[BM][32];
    __shared__ ushort_t Bs[128][32];
    const int tid  = threadIdx.x;
    const int lane = tid & 63;
    const int w    = tid >> 6;
    const int wr   = w >> 1, wc = w & 1;
    const int m0   = blockIdx.x * BM;
    const int n0   = blockIdx.y * 128;
    const int l15  = lane & 15;
    const int lg   = lane >> 4;
    const int srow = lane >> 2;
    const int scol = (lane & 3) * 8;

    f32x4 acc[MF][4] = {};

    for (int k0 = 0; k0 < K; k0 += 32) {
#pragma unroll
        for (int j = 0; j < BM / 64; j++) {
            const int rbase = w * (BM / 4) + j * 16;
            gload16(A + (size_t)(m0 + rbase + srow) * K + k0 + scol, &As[rbase][0]);
        }
#pragma unroll
        for (int j = 0; j < 2; j++) {
            const int rbase = w * 32 + j * 16;
            gload16(Bw + (size_t)(n0 + rbase + srow) * K + k0 + scol, &Bs[rbase][0]);
        }
        __syncthreads();
        bf16x8 af[MF], bfr[4];
#pragma unroll
        for (int i = 0; i < MF; i++) af[i]  = *(const bf16x8*)&As[wr*(BM/2) + i*16 + l15][lg*8];
#pragma unroll
        for (int i = 0; i < 4;  i++) bfr[i] = *(const bf16x8*)&Bs[wc*64 + i*16 + l15][lg*8];
#pragma unroll
        for (int mf = 0; mf < MF; mf++)
#pragma unroll
            for (int nf = 0; nf < 4; nf++)
                acc[mf][nf] = __builtin_amdgcn_mfma_f32_16x16x32_bf16(af[mf], bfr[nf], acc[mf][nf], 0, 0, 0);
        __syncthreads();
    }

#pragma unroll
    for (int mf = 0; mf < MF; mf++) {
#pragma unroll
        for (int nf = 0; nf < 4; nf++) {
            const int col = n0 + wc*64 + nf*16 + l15;
            if constexpr (MODE == 2) {
                const float bv = b0[col];
#pragma unroll
                for (int r = 0; r < 4; r++) {
                    const int row = m0 + wr*(BM/2) + mf*16 + lg*4 + r;
                    ((float*)out0)[(size_t)row * N + col] = acc[mf][nf][r] + bv;
                }
            } else {
                const int mat = col >> 10;
                const int c   = col & 1023;
                const int h   = c >> 6, dh = c & 63;
                const float* bp = (mat == 0) ? b0 : ((mat == 1) ? b1 : b2);
                const float bv = bp[c];
#pragma unroll
                for (int r = 0; r < 4; r++) {
                    const int row = m0 + wr*(BM/2) + mf*16 + lg*4 + r;
                    const int b = row >> 11, s = row & 2047;
                    const float v = acc[mf][nf][r] + bv;
                    if (mat == 0)
                        ((ushort_t*)out0)[((size_t)(b*NHEAD + h) * S_LEN + s) * DHEAD + dh] = f2bf(v);
                    else if (mat == 1)
                        ((ushort_t*)out1)[((size_t)(b*NHEAD + h) * S_LEN + s) * DHEAD + dh] = f2bf(v);
                    else
                        ((ushort_t*)out2)[((size_t)(b*NHEAD + h) * DHEAD + dh) * S_LEN + s] = f2bf(v);
                }
            }
        }
    }
}

// Flash attention, causal. Q,K: [B][H][S][DH] bf16. Vt: [B][H][DH][S] bf16.
// NO K/V LDS staging (L2-resident), NO barriers: 4 independent 16-row
// q-strips per block. Heavy strips dispatched first (reversed x = LPT).
__launch_bounds__(256)
__global__ void attn_fwd(const ushort_t* __restrict__ Q, const ushort_t* __restrict__ Kh,
                         const ushort_t* __restrict__ Vt, ushort_t* __restrict__ Aout) {
    __shared__ ushort_t Ps[4][16][72];       // per-wave P round-trip only
    const int tid  = threadIdx.x;
    const int lane = tid & 63;
    const int w    = tid >> 6;
    const int l15  = lane & 15, lg = lane >> 4;
    const int bh   = blockIdx.y;
    const int qt   = (gridDim.x - 1) - blockIdx.x;
    const int q0   = qt * 64;
    const int qw   = q0 + w * 16;
    const size_t qkbase = (size_t)bh * S_LEN * DHEAD;
    const size_t vtbase = (size_t)bh * DHEAD * S_LEN;
    const float SL2E = SCALE_F * 1.44269504f;   // fold scale + log2(e): use exp2

    bf16x8 aq[2];
#pragma unroll
    for (int kc = 0; kc < 2; kc++)
        aq[kc] = *(const bf16x8*)(Q + qkbase + (size_t)(qw + l15) * DHEAD + kc*32 + lg*8);

    float mrow[4], lrow[4];
    f32x4 o[4] = {};
#pragma unroll
    for (int r = 0; r < 4; r++) { mrow[r] = -3.0e38f; lrow[r] = 0.0f; }

    const int nt = qt + 1;

    for (int t = 0; t < nt; t++) {
        const int kv0 = t * 64;
        const ushort_t* kp = Kh + qkbase + (size_t)kv0 * DHEAD;
        const ushort_t* vp = Vt + vtbase + kv0;

        // K fragments direct from global (L2)
        bf16x8 bkr[2][4];
#pragma unroll
        for (int kc = 0; kc < 2; kc++)
#pragma unroll
            for (int nf = 0; nf < 4; nf++)
                bkr[kc][nf] = *(const bf16x8*)(kp + (size_t)(nf*16 + l15) * DHEAD + kc*32 + lg*8);

        // S = Q K^T  (16 q-rows x 64 kv-cols per wave)
        f32x4 sacc[4] = {};
        __builtin_amdgcn_s_setprio(1);
#pragma unroll
        for (int nf = 0; nf < 4; nf++)
#pragma unroll
            for (int kc = 0; kc < 2; kc++)
                sacc[nf] = __builtin_amdgcn_mfma_f32_16x16x32_bf16(aq[kc], bkr[kc][nf], sacc[nf], 0, 0, 0);
        __builtin_amdgcn_s_setprio(0);

        // V fragments issued now; latency hides under softmax VALU
        bf16x8 bvr[2][4];
#pragma unroll
        for (int kc = 0; kc < 2; kc++)
#pragma unroll
            for (int nf = 0; nf < 4; nf++)
                bvr[kc][nf] = *(const bf16x8*)(vp + (size_t)(nf*16 + l15) * S_LEN + kc*32 + lg*8);

        // scale(+log2e) + causal mask + online softmax in exp2 domain
        float mx[4] = {-3.0e38f, -3.0e38f, -3.0e38f, -3.0e38f};
#pragma unroll
        for (int nf = 0; nf < 4; nf++) {
            const int colk = kv0 + nf*16 + l15;
#pragma unroll
            for (int r = 0; r < 4; r++) {
                const int rowq = qw + lg*4 + r;
                float v = sacc[nf][r] * SL2E;
                if (colk > rowq) v = -3.0e38f;
                sacc[nf][r] = v;
                mx[r] = fmaxf(mx[r], v);
            }
        }
#pragma unroll
        for (int r = 0; r < 4; r++)
#pragma unroll
            for (int m = 1; m < 16; m <<= 1) mx[r] = fmaxf(mx[r], __shfl_xor(mx[r], m));

        float corr[4], rs[4];
#pragma unroll
        for (int r = 0; r < 4; r++) {
            const float mn = fmaxf(mrow[r], mx[r]);
            corr[r] = exp2f(mrow[r] - mn);
            mrow[r] = mn;
            rs[r] = 0.0f;
        }
#pragma unroll
        for (int nf = 0; nf < 4; nf++)
#pragma unroll
            for (int r = 0; r < 4; r++) {
                const float p = exp2f(sacc[nf][r] - mrow[r]);
                rs[r] += p;
                Ps[w][lg*4 + r][nf*16 + l15] = f2bf(p);
            }
#pragma unroll
        for (int r = 0; r < 4; r++) {
#pragma unroll
            for (int m = 1; m < 16; m <<= 1) rs[r] += __shfl_xor(rs[r], m);
            lrow[r] = lrow[r] * corr[r] + rs[r];
        }
#pragma unroll
        for (int nf = 0; nf < 4; nf++)
#pragma unroll
            for (int r = 0; r < 4; r++) o[nf][r] *= corr[r];

        // O += P @ V
        __builtin_amdgcn_s_setprio(1);
#pragma unroll
        for (int kc = 0; kc < 2; kc++) {
            bf16x8 pa = *(const bf16x8*)&Ps[w][l15][kc*32 + lg*8];
#pragma unroll
            for (int nf = 0; nf < 4; nf++)
                o[nf] = __builtin_amdgcn_mfma_f32_16x16x32_bf16(pa, bvr[kc][nf], o[nf], 0, 0, 0);
        }
        __builtin_amdgcn_s_setprio(0);
    }

    // epilogue: O /= l, merge heads
    const int b = bh >> 4, h = bh & 15;
#pragma unroll
    for (int r = 0; r < 4; r++) {
        const float inv = 1.0f / lrow[r];
        const int rowq = qw + lg*4 + r;
#pragma unroll
        for (int nf = 0; nf < 4; nf++) {
            const float v = o[nf][r] * inv;
            Aout[((size_t)(b * S_LEN) + rowq) * DMODEL + h*DHEAD + nf*16 + l15] = f2bf(v);
        }
    }
}

extern "C" void kernel_launch(void* const* d_in, const int* in_sizes, int n_in,
                              void* d_out, int out_size, void* d_ws, size_t ws_size,
                              hipStream_t stream) {
    (void)in_sizes; (void)n_in; (void)out_size; (void)ws_size;
    const float* x  = (const float*)d_in[0];
    const float* Wq = (const float*)d_in[2];
    const float* bq = (const float*)d_in[3];
    const float* Wk = (const float*)d_in[4];
    const float* bk = (const float*)d_in[5];
    const float* Wv = (const float*)d_in[6];
    const float* bv = (const float*)d_in[7];
    const float* Wo = (const float*)d_in[8];
    const float* bo = (const float*)d_in[9];

    char* ws = (char*)d_ws;
    ushort_t* xb    = (ushort_t*)(ws);                 // 4096x1024 bf16  (8 MB)
    ushort_t* Wqkvb = (ushort_t*)(ws + (8u  << 20));   // 3072x1024 bf16  (6 MB)
    ushort_t* Wob   = (ushort_t*)(ws + (14u << 20));   // 1024x1024 bf16  (2 MB)
    ushort_t* Qh    = (ushort_t*)(ws + (16u << 20));   // [B][H][S][DH]   (8 MB)
    ushort_t* Kh    = (ushort_t*)(ws + (24u << 20));   // [B][H][S][DH]   (8 MB)
    ushort_t* Vth   = (ushort_t*)(ws + (32u << 20));   // [B][H][DH][S]   (8 MB)
    ushort_t* Ao    = (ushort_t*)(ws + (40u << 20));   // [B][S][D] bf16  (8 MB)

    cast_all<<<2048, 256, 0, stream>>>(x, Wq, Wk, Wv, Wo, xb, 2097152);

    gemm_bt<0, 128><<<dim3(32, 24), 256, 0, stream>>>(xb, Wqkvb, bq, bk, bv,
                                                      Qh, Kh, Vth, 2*S_LEN, 3*DMODEL, DMODEL);

    attn_fwd<<<dim3(S_LEN/64, 2*NHEAD), 256, 0, stream>>>(Qh, Kh, Vth, Ao);

    gemm_bt<2, 64><<<dim3(64, 8), 256, 0, stream>>>(Ao, Wob, bo, nullptr, nullptr,
                                                    d_out, nullptr, nullptr, 2*S_LEN, DMODEL, DMODEL);
}

// Round 4
// 228.655 us; speedup vs baseline: 1.3942x; 1.3942x over previous
//
#include <hip/hip_runtime.h>

#define S_LEN  2048
#define DMODEL 1024
#define NHEAD  16
#define DHEAD  64
#define SCALE_F 0.125f

typedef unsigned short ushort_t;
typedef __attribute__((ext_vector_type(8))) short bf16x8;
typedef __attribute__((ext_vector_type(4))) float f32x4;

typedef __attribute__((address_space(1))) void gv_t;
typedef __attribute__((address_space(3))) void lv_t;

__device__ __forceinline__ ushort_t f2bf(float f) {
    unsigned u = __builtin_bit_cast(unsigned, f);
    unsigned r = (u + 0x7FFFu + ((u >> 16) & 1u)) >> 16;
    return (ushort_t)r;
}

__device__ __forceinline__ void gload16(const ushort_t* g, ushort_t* l) {
    __builtin_amdgcn_global_load_lds((gv_t*)g, (lv_t*)l, 16, 0, 0);
}

// Cast x, Wq, Wk, Wv, Wo (f32) into one contiguous bf16 region.
__global__ void cast_all(const float* __restrict__ x,
                         const float* __restrict__ Wq, const float* __restrict__ Wk,
                         const float* __restrict__ Wv, const float* __restrict__ Wo,
                         ushort_t* __restrict__ dst, int n4) {
    int i = blockIdx.x * blockDim.x + threadIdx.x;
    int stride = gridDim.x * blockDim.x;
    for (int idx = i; idx < n4; idx += stride) {
        const float* src; int off;
        if (idx < 1048576)      { src = x;  off = idx; }
        else if (idx < 1310720) { src = Wq; off = idx - 1048576; }
        else if (idx < 1572864) { src = Wk; off = idx - 1310720; }
        else if (idx < 1835008) { src = Wv; off = idx - 1572864; }
        else                    { src = Wo; off = idx - 1835008; }
        float4 f = ((const float4*)src)[off];
        ushort4 o;
        o.x = f2bf(f.x); o.y = f2bf(f.y); o.z = f2bf(f.z); o.w = f2bf(f.w);
        ((ushort4*)dst)[idx] = o;
    }
}

// C = A @ B^T + bias.  A: [M][K] bf16, Bw: [N][K] bf16 (row-major, K-contig).
// MODE 0 (BM=128): fused QKV epilogue, N=3072: mat=col>>10 selects Q/K/V dest.
// MODE 2 (BM=64): out0 = f32 flat [M][N].
template<int MODE, int BM>
__launch_bounds__(256)
__global__ void gemm_bt(const ushort_t* __restrict__ A, const ushort_t* __restrict__ Bw,
                        const float* __restrict__ b0, const float* __restrict__ b1,
                        const float* __restrict__ b2,
                        void* __restrict__ out0, void* __restrict__ out1, void* __restrict__ out2,
                        int M, int N, int K) {
    constexpr int MF = BM / 32;
    __shared__ ushort_t As[BM][32];
    __shared__ ushort_t Bs[128][32];
    const int tid  = threadIdx.x;
    const int lane = tid & 63;
    const int w    = tid >> 6;
    const int wr   = w >> 1, wc = w & 1;
    const int m0   = blockIdx.x * BM;
    const int n0   = blockIdx.y * 128;
    const int l15  = lane & 15;
    const int lg   = lane >> 4;
    const int srow = lane >> 2;
    const int scol = (lane & 3) * 8;

    f32x4 acc[MF][4] = {};

    for (int k0 = 0; k0 < K; k0 += 32) {
#pragma unroll
        for (int j = 0; j < BM / 64; j++) {
            const int rbase = w * (BM / 4) + j * 16;
            gload16(A + (size_t)(m0 + rbase + srow) * K + k0 + scol, &As[rbase][0]);
        }
#pragma unroll
        for (int j = 0; j < 2; j++) {
            const int rbase = w * 32 + j * 16;
            gload16(Bw + (size_t)(n0 + rbase + srow) * K + k0 + scol, &Bs[rbase][0]);
        }
        __syncthreads();
        bf16x8 af[MF], bfr[4];
#pragma unroll
        for (int i = 0; i < MF; i++) af[i]  = *(const bf16x8*)&As[wr*(BM/2) + i*16 + l15][lg*8];
#pragma unroll
        for (int i = 0; i < 4;  i++) bfr[i] = *(const bf16x8*)&Bs[wc*64 + i*16 + l15][lg*8];
#pragma unroll
        for (int mf = 0; mf < MF; mf++)
#pragma unroll
            for (int nf = 0; nf < 4; nf++)
                acc[mf][nf] = __builtin_amdgcn_mfma_f32_16x16x32_bf16(af[mf], bfr[nf], acc[mf][nf], 0, 0, 0);
        __syncthreads();
    }

#pragma unroll
    for (int mf = 0; mf < MF; mf++) {
#pragma unroll
        for (int nf = 0; nf < 4; nf++) {
            const int col = n0 + wc*64 + nf*16 + l15;
            if constexpr (MODE == 2) {
                const float bv = b0[col];
#pragma unroll
                for (int r = 0; r < 4; r++) {
                    const int row = m0 + wr*(BM/2) + mf*16 + lg*4 + r;
                    ((float*)out0)[(size_t)row * N + col] = acc[mf][nf][r] + bv;
                }
            } else {
                const int mat = col >> 10;
                const int c   = col & 1023;
                const int h   = c >> 6, dh = c & 63;
                const float* bp = (mat == 0) ? b0 : ((mat == 1) ? b1 : b2);
                const float bv = bp[c];
#pragma unroll
                for (int r = 0; r < 4; r++) {
                    const int row = m0 + wr*(BM/2) + mf*16 + lg*4 + r;
                    const int b = row >> 11, s = row & 2047;
                    const float v = acc[mf][nf][r] + bv;
                    if (mat == 0)
                        ((ushort_t*)out0)[((size_t)(b*NHEAD + h) * S_LEN + s) * DHEAD + dh] = f2bf(v);
                    else if (mat == 1)
                        ((ushort_t*)out1)[((size_t)(b*NHEAD + h) * S_LEN + s) * DHEAD + dh] = f2bf(v);
                    else
                        ((ushort_t*)out2)[((size_t)(b*NHEAD + h) * DHEAD + dh) * S_LEN + s] = f2bf(v);
                }
            }
        }
    }
}

// Flash attention, causal. Q,K: [B][H][S][DH] bf16. Vt: [B][H][DH][S] bf16.
// Double-buffered K/V staging via global_load_lds (linear dest + XOR-swizzled
// global source; reads apply the same XOR). One barrier per tile; stage of
// tile t+1 issued before compute of tile t (2-phase pipeline).
__launch_bounds__(256)
__global__ void attn_fwd(const ushort_t* __restrict__ Q, const ushort_t* __restrict__ Kh,
                         const ushort_t* __restrict__ Vt, ushort_t* __restrict__ Aout) {
    __shared__ ushort_t Ks[2][64][64];
    __shared__ ushort_t Vs[2][64][64];       // [dh][kv]
    __shared__ ushort_t Ps[4][16][72];       // per-wave P round-trip
    const int tid  = threadIdx.x;
    const int lane = tid & 63;
    const int w    = tid >> 6;
    const int l15  = lane & 15, lg = lane >> 4;
    const int bh   = blockIdx.y;
    const int qt   = (gridDim.x - 1) - blockIdx.x;   // LPT: heavy tiles first
    const int q0   = qt * 64;
    const int qw   = q0 + w * 16;
    const size_t qkbase = (size_t)bh * S_LEN * DHEAD;
    const size_t vtbase = (size_t)bh * DHEAD * S_LEN;
    const float SL2E = SCALE_F * 1.44269504f;        // exp2-domain softmax

    // staging address math: instr j covers LDS rows 8j..8j+7 (1 KB linear);
    // lane i -> row 8j+(i>>3), LDS col (i&7)*8 elems, which holds global col
    // ((i&7)^((i>>3)&7))*8  (XOR swizzle, both-sides).
    const int rsub = lane >> 3;                      // 0..7
    const int csw  = ((lane & 7) ^ rsub) * 8;        // swizzled global col (elems)

    bf16x8 aq[2];
#pragma unroll
    for (int kc = 0; kc < 2; kc++)
        aq[kc] = *(const bf16x8*)(Q + qkbase + (size_t)(qw + l15) * DHEAD + kc*32 + lg*8);

    float mrow[4], lrow[4];
    f32x4 o[4] = {};
#pragma unroll
    for (int r = 0; r < 4; r++) { mrow[r] = -3.0e38f; lrow[r] = 0.0f; }

    const int nt = qt + 1;

    auto stage = [&](int buf, int t) {
        const int kv0 = t * 64;
        const ushort_t* kp = Kh + qkbase + (size_t)kv0 * DHEAD;
        const ushort_t* vp = Vt + vtbase + kv0;
#pragma unroll
        for (int j2 = 0; j2 < 2; j2++) {
            const int j  = w * 2 + j2;               // 0..7
            const int rg = j * 8 + rsub;             // tile row
            gload16(kp + (size_t)rg * DHEAD + csw, &Ks[buf][j*8][0]);
            gload16(vp + (size_t)rg * S_LEN + csw, &Vs[buf][j*8][0]);
        }
    };

    stage(0, 0);
    __syncthreads();                                 // drains vmcnt

    for (int t = 0; t < nt; t++) {
        const int cur = t & 1;
        if (t + 1 < nt) stage(cur ^ 1, t + 1);       // prefetch overlaps compute
        const int kv0 = t * 64;
        const int swz = (l15 & 7) * 8;               // read-side XOR (elems)

        // K fragments from LDS (swizzled)
        bf16x8 bkr[2][4];
#pragma unroll
        for (int kc = 0; kc < 2; kc++)
#pragma unroll
            for (int nf = 0; nf < 4; nf++)
                bkr[kc][nf] = *(const bf16x8*)&Ks[cur][nf*16 + l15][(kc*32 + lg*8) ^ swz];

        // S = Q K^T  (16 q-rows x 64 kv-cols per wave)
        f32x4 sacc[4] = {};
        __builtin_amdgcn_s_setprio(1);
#pragma unroll
        for (int nf = 0; nf < 4; nf++)
#pragma unroll
            for (int kc = 0; kc < 2; kc++)
                sacc[nf] = __builtin_amdgcn_mfma_f32_16x16x32_bf16(aq[kc], bkr[kc][nf], sacc[nf], 0, 0, 0);
        __builtin_amdgcn_s_setprio(0);

        // scale + causal mask + online softmax (exp2 domain)
        float mx[4] = {-3.0e38f, -3.0e38f, -3.0e38f, -3.0e38f};
#pragma unroll
        for (int nf = 0; nf < 4; nf++) {
            const int colk = kv0 + nf*16 + l15;
#pragma unroll
            for (int r = 0; r < 4; r++) {
                const int rowq = qw + lg*4 + r;
                float v = sacc[nf][r] * SL2E;
                if (colk > rowq) v = -3.0e38f;
                sacc[nf][r] = v;
                mx[r] = fmaxf(mx[r], v);
            }
        }
#pragma unroll
        for (int r = 0; r < 4; r++)
#pragma unroll
            for (int m = 1; m < 16; m <<= 1) mx[r] = fmaxf(mx[r], __shfl_xor(mx[r], m));

        float corr[4], rs[4];
#pragma unroll
        for (int r = 0; r < 4; r++) {
            const float mn = fmaxf(mrow[r], mx[r]);
            corr[r] = exp2f(mrow[r] - mn);
            mrow[r] = mn;
            rs[r] = 0.0f;
        }
#pragma unroll
        for (int nf = 0; nf < 4; nf++)
#pragma unroll
            for (int r = 0; r < 4; r++) {
                const float p = exp2f(sacc[nf][r] - mrow[r]);
                rs[r] += p;
                Ps[w][lg*4 + r][nf*16 + l15] = f2bf(p);
            }
#pragma unroll
        for (int r = 0; r < 4; r++) {
#pragma unroll
            for (int m = 1; m < 16; m <<= 1) rs[r] += __shfl_xor(rs[r], m);
            lrow[r] = lrow[r] * corr[r] + rs[r];
        }
#pragma unroll
        for (int nf = 0; nf < 4; nf++)
#pragma unroll
            for (int r = 0; r < 4; r++) o[nf][r] *= corr[r];

        // O += P @ V   (V fragments from LDS, swizzled)
        __builtin_amdgcn_s_setprio(1);
#pragma unroll
        for (int kc = 0; kc < 2; kc++) {
            bf16x8 pa = *(const bf16x8*)&Ps[w][l15][kc*32 + lg*8];
#pragma unroll
            for (int nf = 0; nf < 4; nf++) {
                bf16x8 bv = *(const bf16x8*)&Vs[cur][nf*16 + l15][(kc*32 + lg*8) ^ swz];
                o[nf] = __builtin_amdgcn_mfma_f32_16x16x32_bf16(pa, bv, o[nf], 0, 0, 0);
            }
        }
        __builtin_amdgcn_s_setprio(0);

        __syncthreads();                             // staged t+1 ready; buf reuse safe
    }

    // epilogue: O /= l, merge heads
    const int b = bh >> 4, h = bh & 15;
#pragma unroll
    for (int r = 0; r < 4; r++) {
        const float inv = 1.0f / lrow[r];
        const int rowq = qw + lg*4 + r;
#pragma unroll
        for (int nf = 0; nf < 4; nf++) {
            const float v = o[nf][r] * inv;
            Aout[((size_t)(b * S_LEN) + rowq) * DMODEL + h*DHEAD + nf*16 + l15] = f2bf(v);
        }
    }
}

extern "C" void kernel_launch(void* const* d_in, const int* in_sizes, int n_in,
                              void* d_out, int out_size, void* d_ws, size_t ws_size,
                              hipStream_t stream) {
    (void)in_sizes; (void)n_in; (void)out_size; (void)ws_size;
    const float* x  = (const float*)d_in[0];
    const float* Wq = (const float*)d_in[2];
    const float* bq = (const float*)d_in[3];
    const float* Wk = (const float*)d_in[4];
    const float* bk = (const float*)d_in[5];
    const float* Wv = (const float*)d_in[6];
    const float* bv = (const float*)d_in[7];
    const float* Wo = (const float*)d_in[8];
    const float* bo = (const float*)d_in[9];

    char* ws = (char*)d_ws;
    ushort_t* xb    = (ushort_t*)(ws);                 // 4096x1024 bf16  (8 MB)
    ushort_t* Wqkvb = (ushort_t*)(ws + (8u  << 20));   // 3072x1024 bf16  (6 MB)
    ushort_t* Wob   = (ushort_t*)(ws + (14u << 20));   // 1024x1024 bf16  (2 MB)
    ushort_t* Qh    = (ushort_t*)(ws + (16u << 20));   // [B][H][S][DH]   (8 MB)
    ushort_t* Kh    = (ushort_t*)(ws + (24u << 20));   // [B][H][S][DH]   (8 MB)
    ushort_t* Vth   = (ushort_t*)(ws + (32u << 20));   // [B][H][DH][S]   (8 MB)
    ushort_t* Ao    = (ushort_t*)(ws + (40u << 20));   // [B][S][D] bf16  (8 MB)

    cast_all<<<2048, 256, 0, stream>>>(x, Wq, Wk, Wv, Wo, xb, 2097152);

    gemm_bt<0, 128><<<dim3(32, 24), 256, 0, stream>>>(xb, Wqkvb, bq, bk, bv,
                                                      Qh, Kh, Vth, 2*S_LEN, 3*DMODEL, DMODEL);

    attn_fwd<<<dim3(S_LEN/64, 2*NHEAD), 256, 0, stream>>>(Qh, Kh, Vth, Ao);

    gemm_bt<2, 64><<<dim3(64, 8), 256, 0, stream>>>(Ao, Wob, bo, nullptr, nullptr,
                                                    d_out, nullptr, nullptr, 2*S_LEN, DMODEL, DMODEL);
}

// Round 5
// 152.410 us; speedup vs baseline: 2.0917x; 1.5003x over previous
//
#include <hip/hip_runtime.h>

#define S_LEN  2048
#define DMODEL 1024
#define NHEAD  16
#define DHEAD  64
#define SCALE_F 0.125f

typedef unsigned short ushort_t;
typedef __attribute__((ext_vector_type(8))) short bf16x8;
typedef __attribute__((ext_vector_type(4))) float f32x4;

typedef __attribute__((address_space(1))) void gv_t;
typedef __attribute__((address_space(3))) void lv_t;

__device__ __forceinline__ ushort_t f2bf(float f) {
    unsigned u = __builtin_bit_cast(unsigned, f);
    unsigned r = (u + 0x7FFFu + ((u >> 16) & 1u)) >> 16;
    return (ushort_t)r;
}

__device__ __forceinline__ void gload16(const ushort_t* g, ushort_t* l) {
    __builtin_amdgcn_global_load_lds((gv_t*)g, (lv_t*)l, 16, 0, 0);
}

// Cast x, Wq, Wk, Wv, Wo (f32) into one contiguous bf16 region.
__global__ void cast_all(const float* __restrict__ x,
                         const float* __restrict__ Wq, const float* __restrict__ Wk,
                         const float* __restrict__ Wv, const float* __restrict__ Wo,
                         ushort_t* __restrict__ dst, int n4) {
    int i = blockIdx.x * blockDim.x + threadIdx.x;
    int stride = gridDim.x * blockDim.x;
    for (int idx = i; idx < n4; idx += stride) {
        const float* src; int off;
        if (idx < 1048576)      { src = x;  off = idx; }
        else if (idx < 1310720) { src = Wq; off = idx - 1048576; }
        else if (idx < 1572864) { src = Wk; off = idx - 1310720; }
        else if (idx < 1835008) { src = Wv; off = idx - 1572864; }
        else                    { src = Wo; off = idx - 1835008; }
        float4 f = ((const float4*)src)[off];
        ushort4 o;
        o.x = f2bf(f.x); o.y = f2bf(f.y); o.z = f2bf(f.z); o.w = f2bf(f.w);
        ((ushort4*)dst)[idx] = o;
    }
}

// C = A @ B^T + bias.  A: [M][K] bf16, Bw: [N][K] bf16 (row-major, K-contig).
// MODE 0 (BM=128): fused QKV epilogue, N=3072: mat=col>>10 selects Q/K/V dest.
// MODE 2 (BM=64): out0 = f32 flat [M][N].
template<int MODE, int BM>
__launch_bounds__(256)
__global__ void gemm_bt(const ushort_t* __restrict__ A, const ushort_t* __restrict__ Bw,
                        const float* __restrict__ b0, const float* __restrict__ b1,
                        const float* __restrict__ b2,
                        void* __restrict__ out0, void* __restrict__ out1, void* __restrict__ out2,
                        int M, int N, int K) {
    constexpr int MF = BM / 32;
    __shared__ ushort_t As[BM][32];
    __shared__ ushort_t Bs[128][32];
    const int tid  = threadIdx.x;
    const int lane = tid & 63;
    const int w    = tid >> 6;
    const int wr   = w >> 1, wc = w & 1;
    const int m0   = blockIdx.x * BM;
    const int n0   = blockIdx.y * 128;
    const int l15  = lane & 15;
    const int lg   = lane >> 4;
    const int srow = lane >> 2;
    const int scol = (lane & 3) * 8;

    f32x4 acc[MF][4] = {};

    for (int k0 = 0; k0 < K; k0 += 32) {
#pragma unroll
        for (int j = 0; j < BM / 64; j++) {
            const int rbase = w * (BM / 4) + j * 16;
            gload16(A + (size_t)(m0 + rbase + srow) * K + k0 + scol, &As[rbase][0]);
        }
#pragma unroll
        for (int j = 0; j < 2; j++) {
            const int rbase = w * 32 + j * 16;
            gload16(Bw + (size_t)(n0 + rbase + srow) * K + k0 + scol, &Bs[rbase][0]);
        }
        __syncthreads();
        bf16x8 af[MF], bfr[4];
#pragma unroll
        for (int i = 0; i < MF; i++) af[i]  = *(const bf16x8*)&As[wr*(BM/2) + i*16 + l15][lg*8];
#pragma unroll
        for (int i = 0; i < 4;  i++) bfr[i] = *(const bf16x8*)&Bs[wc*64 + i*16 + l15][lg*8];
#pragma unroll
        for (int mf = 0; mf < MF; mf++)
#pragma unroll
            for (int nf = 0; nf < 4; nf++)
                acc[mf][nf] = __builtin_amdgcn_mfma_f32_16x16x32_bf16(af[mf], bfr[nf], acc[mf][nf], 0, 0, 0);
        __syncthreads();
    }

#pragma unroll
    for (int mf = 0; mf < MF; mf++) {
#pragma unroll
        for (int nf = 0; nf < 4; nf++) {
            const int col = n0 + wc*64 + nf*16 + l15;
            if constexpr (MODE == 2) {
                const float bv = b0[col];
#pragma unroll
                for (int r = 0; r < 4; r++) {
                    const int row = m0 + wr*(BM/2) + mf*16 + lg*4 + r;
                    ((float*)out0)[(size_t)row * N + col] = acc[mf][nf][r] + bv;
                }
            } else {
                const int mat = col >> 10;
                const int c   = col & 1023;
                const int h   = c >> 6, dh = c & 63;
                const float* bp = (mat == 0) ? b0 : ((mat == 1) ? b1 : b2);
                const float bv = bp[c];
#pragma unroll
                for (int r = 0; r < 4; r++) {
                    const int row = m0 + wr*(BM/2) + mf*16 + lg*4 + r;
                    const int b = row >> 11, s = row & 2047;
                    const float v = acc[mf][nf][r] + bv;
                    if (mat == 0)
                        ((ushort_t*)out0)[((size_t)(b*NHEAD + h) * S_LEN + s) * DHEAD + dh] = f2bf(v);
                    else if (mat == 1)
                        ((ushort_t*)out1)[((size_t)(b*NHEAD + h) * S_LEN + s) * DHEAD + dh] = f2bf(v);
                    else
                        ((ushort_t*)out2)[((size_t)(b*NHEAD + h) * DHEAD + dh) * S_LEN + s] = f2bf(v);
                }
            }
        }
    }
}

// Flash attention, causal, pair-balanced: block (p, bh) handles q-tiles p and
// 31-p (both 64 rows, 16/wave) -> uniform 33 compute-steps per block.
// Swapped QK^T (S^T = mfma(K,Q)): q = lane&15, kv = (lane>>4)*4+r ->
// softmax = in-lane tree + 2 shuffles. K/V staged once, shared by both strips.
__launch_bounds__(256, 3)
__global__ void attn_fwd(const ushort_t* __restrict__ Q, const ushort_t* __restrict__ Kh,
                         const ushort_t* __restrict__ Vt, ushort_t* __restrict__ Aout) {
    __shared__ ushort_t Ks[64][64];
    __shared__ ushort_t Vs[64][64];          // [dh][kv]
    __shared__ ushort_t Ps[4][16][72];       // per-wave P round-trip [q][kv]
    const int tid  = threadIdx.x;
    const int lane = tid & 63;
    const int w    = tid >> 6;
    const int l15  = lane & 15, lg = lane >> 4;
    const int bh   = blockIdx.y;
    const int qta  = blockIdx.x;             // 0..15
    const int qtb  = 31 - qta;               // 16..31
    const size_t qkbase = (size_t)bh * S_LEN * DHEAD;
    const size_t vtbase = (size_t)bh * DHEAD * S_LEN;
    const float SL2E = SCALE_F * 1.44269504f;

    // staging swizzle (source-side XOR, linear LDS dest)
    const int rsub = lane >> 3;                      // 0..7
    const int csw  = ((lane & 7) ^ rsub) * 8;        // swizzled global col
    const int swz  = (l15 & 7) * 8;                  // read-side XOR

    const int qa = qta * 64 + w * 16;
    const int qb = qtb * 64 + w * 16;

    bf16x8 aqA[2], aqB[2];
#pragma unroll
    for (int kc = 0; kc < 2; kc++) {
        aqA[kc] = *(const bf16x8*)(Q + qkbase + (size_t)(qa + l15) * DHEAD + kc*32 + lg*8);
        aqB[kc] = *(const bf16x8*)(Q + qkbase + (size_t)(qb + l15) * DHEAD + kc*32 + lg*8);
    }

    float mA = -3.0e38f, lA = 0.0f, mB = -3.0e38f, lB = 0.0f;
    f32x4 oA[4] = {}, oB[4] = {};

    auto stage = [&](int t) {
        const int kv0 = t * 64;
        const ushort_t* kp = Kh + qkbase + (size_t)kv0 * DHEAD;
        const ushort_t* vp = Vt + vtbase + kv0;
#pragma unroll
        for (int j2 = 0; j2 < 2; j2++) {
            const int j  = w * 2 + j2;               // 0..7
            const int rg = j * 8 + rsub;
            gload16(kp + (size_t)rg * DHEAD + csw, &Ks[j*8][0]);
            gload16(vp + (size_t)rg * S_LEN + csw, &Vs[j*8][0]);
        }
    };

    auto compute = [&](int t, int qbase, bf16x8 (&aq)[2], float& m, float& l, f32x4 (&o)[4]) {
        const int kv0  = t * 64;
        const int rowq = qbase + l15;
        f32x4 sacc[4] = {};
        __builtin_amdgcn_s_setprio(1);
#pragma unroll
        for (int kc = 0; kc < 2; kc++)
#pragma unroll
            for (int nf = 0; nf < 4; nf++) {
                bf16x8 bk = *(const bf16x8*)&Ks[nf*16 + l15][(kc*32 + lg*8) ^ swz];
                sacc[nf] = __builtin_amdgcn_mfma_f32_16x16x32_bf16(bk, aq[kc], sacc[nf], 0, 0, 0);
            }
        __builtin_amdgcn_s_setprio(0);

        // scale + causal mask + in-lane max (16 scores/lane, one q-row)
        float mx = -3.0e38f;
#pragma unroll
        for (int nf = 0; nf < 4; nf++)
#pragma unroll
            for (int r = 0; r < 4; r++) {
                const int colk = kv0 + nf*16 + lg*4 + r;
                float v = sacc[nf][r] * SL2E;
                v = (colk > rowq) ? -3.0e38f : v;
                sacc[nf][r] = v;
                mx = fmaxf(mx, v);
            }
        mx = fmaxf(mx, __shfl_xor(mx, 16));
        mx = fmaxf(mx, __shfl_xor(mx, 32));

        const float mn   = fmaxf(m, mx);
        const float corr = exp2f(m - mn);
        m = mn;

        float s = 0.0f;
#pragma unroll
        for (int nf = 0; nf < 4; nf++) {
            ushort_t pk[4];
#pragma unroll
            for (int r = 0; r < 4; r++) {
                const float p = exp2f(sacc[nf][r] - mn);
                s += p;
                pk[r] = f2bf(p);
            }
            *(ushort4*)&Ps[w][l15][nf*16 + lg*4] = *(ushort4*)pk;
        }
        s += __shfl_xor(s, 16);
        s += __shfl_xor(s, 32);
        l = l * corr + s;

        float cf[4];
#pragma unroll
        for (int r = 0; r < 4; r++) cf[r] = __shfl(corr, lg*4 + r);
#pragma unroll
        for (int nf = 0; nf < 4; nf++)
#pragma unroll
            for (int r = 0; r < 4; r++) o[nf][r] *= cf[r];

        __builtin_amdgcn_s_setprio(1);
#pragma unroll
        for (int kc = 0; kc < 2; kc++) {
            bf16x8 pa = *(const bf16x8*)&Ps[w][l15][kc*32 + lg*8];
#pragma unroll
            for (int nf = 0; nf < 4; nf++) {
                bf16x8 bv = *(const bf16x8*)&Vs[nf*16 + l15][(kc*32 + lg*8) ^ swz];
                o[nf] = __builtin_amdgcn_mfma_f32_16x16x32_bf16(pa, bv, o[nf], 0, 0, 0);
            }
        }
        __builtin_amdgcn_s_setprio(0);
    };

    for (int t = 0; t <= qta; t++) {                 // both strips need these tiles
        stage(t);
        __syncthreads();
        compute(t, qa, aqA, mA, lA, oA);
        compute(t, qb, aqB, mB, lB, oB);
        __syncthreads();
    }
    for (int t = qta + 1; t <= qtb; t++) {           // strip B only
        stage(t);
        __syncthreads();
        compute(t, qb, aqB, mB, lB, oB);
        __syncthreads();
    }

    // epilogue: O /= l (per q-row via shuffle), merge heads
    const int b = bh >> 4, h = bh & 15;
    const float invA = 1.0f / lA, invB = 1.0f / lB;
#pragma unroll
    for (int r = 0; r < 4; r++) {
        const float ia = __shfl(invA, lg*4 + r);
        const float ib = __shfl(invB, lg*4 + r);
        const int rowa = qa + lg*4 + r;
        const int rowb = qb + lg*4 + r;
#pragma unroll
        for (int nf = 0; nf < 4; nf++) {
            Aout[((size_t)(b * S_LEN) + rowa) * DMODEL + h*DHEAD + nf*16 + l15] = f2bf(oA[nf][r] * ia);
            Aout[((size_t)(b * S_LEN) + rowb) * DMODEL + h*DHEAD + nf*16 + l15] = f2bf(oB[nf][r] * ib);
        }
    }
}

extern "C" void kernel_launch(void* const* d_in, const int* in_sizes, int n_in,
                              void* d_out, int out_size, void* d_ws, size_t ws_size,
                              hipStream_t stream) {
    (void)in_sizes; (void)n_in; (void)out_size; (void)ws_size;
    const float* x  = (const float*)d_in[0];
    const float* Wq = (const float*)d_in[2];
    const float* bq = (const float*)d_in[3];
    const float* Wk = (const float*)d_in[4];
    const float* bk = (const float*)d_in[5];
    const float* Wv = (const float*)d_in[6];
    const float* bv = (const float*)d_in[7];
    const float* Wo = (const float*)d_in[8];
    const float* bo = (const float*)d_in[9];

    char* ws = (char*)d_ws;
    ushort_t* xb    = (ushort_t*)(ws);                 // 4096x1024 bf16  (8 MB)
    ushort_t* Wqkvb = (ushort_t*)(ws + (8u  << 20));   // 3072x1024 bf16  (6 MB)
    ushort_t* Wob   = (ushort_t*)(ws + (14u << 20));   // 1024x1024 bf16  (2 MB)
    ushort_t* Qh    = (ushort_t*)(ws + (16u << 20));   // [B][H][S][DH]   (8 MB)
    ushort_t* Kh    = (ushort_t*)(ws + (24u << 20));   // [B][H][S][DH]   (8 MB)
    ushort_t* Vth   = (ushort_t*)(ws + (32u << 20));   // [B][H][DH][S]   (8 MB)
    ushort_t* Ao    = (ushort_t*)(ws + (40u << 20));   // [B][S][D] bf16  (8 MB)

    cast_all<<<2048, 256, 0, stream>>>(x, Wq, Wk, Wv, Wo, xb, 2097152);

    gemm_bt<0, 128><<<dim3(32, 24), 256, 0, stream>>>(xb, Wqkvb, bq, bk, bv,
                                                      Qh, Kh, Vth, 2*S_LEN, 3*DMODEL, DMODEL);

    attn_fwd<<<dim3(16, 2*NHEAD), 256, 0, stream>>>(Qh, Kh, Vth, Ao);

    gemm_bt<2, 64><<<dim3(64, 8), 256, 0, stream>>>(Ao, Wob, bo, nullptr, nullptr,
                                                    d_out, nullptr, nullptr, 2*S_LEN, DMODEL, DMODEL);
}

// Round 6
// 127.735 us; speedup vs baseline: 2.4957x; 1.1932x over previous
//
#include <hip/hip_runtime.h>

#define S_LEN  2048
#define DMODEL 1024
#define NHEAD  16
#define DHEAD  64
#define SCALE_F 0.125f

typedef unsigned short ushort_t;
typedef __attribute__((ext_vector_type(8))) short bf16x8;
typedef __attribute__((ext_vector_type(4))) float f32x4;

typedef __attribute__((address_space(1))) void gv_t;
typedef __attribute__((address_space(3))) void lv_t;

__device__ __forceinline__ ushort_t f2bf(float f) {
    unsigned u = __builtin_bit_cast(unsigned, f);
    unsigned r = (u + 0x7FFFu + ((u >> 16) & 1u)) >> 16;
    return (ushort_t)r;
}

__device__ __forceinline__ void gload16(const ushort_t* g, ushort_t* l) {
    __builtin_amdgcn_global_load_lds((gv_t*)g, (lv_t*)l, 16, 0, 0);
}

// Cast x, Wq, Wk, Wv, Wo (f32) into one contiguous bf16 region.
__global__ void cast_all(const float* __restrict__ x,
                         const float* __restrict__ Wq, const float* __restrict__ Wk,
                         const float* __restrict__ Wv, const float* __restrict__ Wo,
                         ushort_t* __restrict__ dst, int n4) {
    int i = blockIdx.x * blockDim.x + threadIdx.x;
    int stride = gridDim.x * blockDim.x;
    for (int idx = i; idx < n4; idx += stride) {
        const float* src; int off;
        if (idx < 1048576)      { src = x;  off = idx; }
        else if (idx < 1310720) { src = Wq; off = idx - 1048576; }
        else if (idx < 1572864) { src = Wk; off = idx - 1310720; }
        else if (idx < 1835008) { src = Wv; off = idx - 1572864; }
        else                    { src = Wo; off = idx - 1835008; }
        float4 f = ((const float4*)src)[off];
        ushort4 o;
        o.x = f2bf(f.x); o.y = f2bf(f.y); o.z = f2bf(f.z); o.w = f2bf(f.w);
        ((ushort4*)dst)[idx] = o;
    }
}

// C = A @ B^T + bias, 2-phase double-buffered K-loop (stage k+1 before
// compute k, one barrier per step).
// MODE 0 (BM=128): fused QKV epilogue, N=3072: mat=col>>10 selects Q/K/V dest.
// MODE 2 (BM=64): out0 = f32 flat [M][N].
template<int MODE, int BM>
__launch_bounds__(256)
__global__ void gemm_bt(const ushort_t* __restrict__ A, const ushort_t* __restrict__ Bw,
                        const float* __restrict__ b0, const float* __restrict__ b1,
                        const float* __restrict__ b2,
                        void* __restrict__ out0, void* __restrict__ out1, void* __restrict__ out2,
                        int M, int N, int K) {
    constexpr int MF = BM / 32;
    __shared__ ushort_t As[2][BM][32];
    __shared__ ushort_t Bs[2][128][32];
    const int tid  = threadIdx.x;
    const int lane = tid & 63;
    const int w    = tid >> 6;
    const int wr   = w >> 1, wc = w & 1;
    const int m0   = blockIdx.x * BM;
    const int n0   = blockIdx.y * 128;
    const int l15  = lane & 15;
    const int lg   = lane >> 4;
    const int srow = lane >> 2;
    const int scol = (lane & 3) * 8;

    f32x4 acc[MF][4] = {};

    auto stage = [&](int buf, int k0) {
#pragma unroll
        for (int j = 0; j < BM / 64; j++) {
            const int rbase = w * (BM / 4) + j * 16;
            gload16(A + (size_t)(m0 + rbase + srow) * K + k0 + scol, &As[buf][rbase][0]);
        }
#pragma unroll
        for (int j = 0; j < 2; j++) {
            const int rbase = w * 32 + j * 16;
            gload16(Bw + (size_t)(n0 + rbase + srow) * K + k0 + scol, &Bs[buf][rbase][0]);
        }
    };

    stage(0, 0);
    __syncthreads();
    int buf = 0;

    for (int k0 = 0; k0 < K; k0 += 32) {
        if (k0 + 32 < K) stage(buf ^ 1, k0 + 32);   // prefetch overlaps compute
        bf16x8 af[MF], bfr[4];
#pragma unroll
        for (int i = 0; i < MF; i++) af[i]  = *(const bf16x8*)&As[buf][wr*(BM/2) + i*16 + l15][lg*8];
#pragma unroll
        for (int i = 0; i < 4;  i++) bfr[i] = *(const bf16x8*)&Bs[buf][wc*64 + i*16 + l15][lg*8];
#pragma unroll
        for (int mf = 0; mf < MF; mf++)
#pragma unroll
            for (int nf = 0; nf < 4; nf++)
                acc[mf][nf] = __builtin_amdgcn_mfma_f32_16x16x32_bf16(af[mf], bfr[nf], acc[mf][nf], 0, 0, 0);
        __syncthreads();                            // prefetch landed; buf free
        buf ^= 1;
    }

#pragma unroll
    for (int mf = 0; mf < MF; mf++) {
#pragma unroll
        for (int nf = 0; nf < 4; nf++) {
            const int col = n0 + wc*64 + nf*16 + l15;
            if constexpr (MODE == 2) {
                const float bv = b0[col];
#pragma unroll
                for (int r = 0; r < 4; r++) {
                    const int row = m0 + wr*(BM/2) + mf*16 + lg*4 + r;
                    ((float*)out0)[(size_t)row * N + col] = acc[mf][nf][r] + bv;
                }
            } else {
                const int mat = col >> 10;
                const int c   = col & 1023;
                const int h   = c >> 6, dh = c & 63;
                const float* bp = (mat == 0) ? b0 : ((mat == 1) ? b1 : b2);
                const float bv = bp[c];
#pragma unroll
                for (int r = 0; r < 4; r++) {
                    const int row = m0 + wr*(BM/2) + mf*16 + lg*4 + r;
                    const int b = row >> 11, s = row & 2047;
                    const float v = acc[mf][nf][r] + bv;
                    if (mat == 0)
                        ((ushort_t*)out0)[((size_t)(b*NHEAD + h) * S_LEN + s) * DHEAD + dh] = f2bf(v);
                    else if (mat == 1)
                        ((ushort_t*)out1)[((size_t)(b*NHEAD + h) * S_LEN + s) * DHEAD + dh] = f2bf(v);
                    else
                        ((ushort_t*)out2)[((size_t)(b*NHEAD + h) * DHEAD + dh) * S_LEN + s] = f2bf(v);
                }
            }
        }
    }
}

// Flash attention, causal, pair-balanced (q-tiles p and 31-p per block),
// swapped QK^T (q = lane&15, kv = (lane>>4)*4+r), double-buffered K/V
// prefetch (stage t+1 before compute t), defer-max rescale (THR=8),
// mask only on the diagonal tile.
__launch_bounds__(256, 3)
__global__ void attn_fwd(const ushort_t* __restrict__ Q, const ushort_t* __restrict__ Kh,
                         const ushort_t* __restrict__ Vt, ushort_t* __restrict__ Aout) {
    __shared__ ushort_t Ks[2][64][64];
    __shared__ ushort_t Vs[2][64][64];       // [dh][kv]
    __shared__ ushort_t Ps[4][16][72];       // per-wave P round-trip [q][kv]
    const int tid  = threadIdx.x;
    const int lane = tid & 63;
    const int w    = tid >> 6;
    const int l15  = lane & 15, lg = lane >> 4;
    const int bh   = blockIdx.y;
    const int qta  = blockIdx.x;             // 0..15
    const int qtb  = 31 - qta;               // 16..31
    const size_t qkbase = (size_t)bh * S_LEN * DHEAD;
    const size_t vtbase = (size_t)bh * DHEAD * S_LEN;
    const float SL2E = SCALE_F * 1.44269504f;

    const int rsub = lane >> 3;                      // staging source swizzle
    const int csw  = ((lane & 7) ^ rsub) * 8;
    const int swz  = (l15 & 7) * 8;                  // read-side XOR

    const int qa = qta * 64 + w * 16;
    const int qb = qtb * 64 + w * 16;

    bf16x8 aqA[2], aqB[2];
#pragma unroll
    for (int kc = 0; kc < 2; kc++) {
        aqA[kc] = *(const bf16x8*)(Q + qkbase + (size_t)(qa + l15) * DHEAD + kc*32 + lg*8);
        aqB[kc] = *(const bf16x8*)(Q + qkbase + (size_t)(qb + l15) * DHEAD + kc*32 + lg*8);
    }

    float mA = -3.0e38f, lA = 0.0f, mB = -3.0e38f, lB = 0.0f;
    f32x4 oA[4] = {}, oB[4] = {};

    auto stage = [&](int buf, int t) {
        const int kv0 = t * 64;
        const ushort_t* kp = Kh + qkbase + (size_t)kv0 * DHEAD;
        const ushort_t* vp = Vt + vtbase + kv0;
#pragma unroll
        for (int j2 = 0; j2 < 2; j2++) {
            const int j  = w * 2 + j2;
            const int rg = j * 8 + rsub;
            gload16(kp + (size_t)rg * DHEAD + csw, &Ks[buf][j*8][0]);
            gload16(vp + (size_t)rg * S_LEN + csw, &Vs[buf][j*8][0]);
        }
    };

    auto compute = [&](int buf, int t, int qbase, bf16x8 (&aq)[2], float& m, float& l,
                       f32x4 (&o)[4], bool domask) {
        const int kv0  = t * 64;
        const int rowq = qbase + l15;
        f32x4 sacc[4] = {};
        __builtin_amdgcn_s_setprio(1);
#pragma unroll
        for (int kc = 0; kc < 2; kc++)
#pragma unroll
            for (int nf = 0; nf < 4; nf++) {
                bf16x8 bk = *(const bf16x8*)&Ks[buf][nf*16 + l15][(kc*32 + lg*8) ^ swz];
                sacc[nf] = __builtin_amdgcn_mfma_f32_16x16x32_bf16(bk, aq[kc], sacc[nf], 0, 0, 0);
            }
        __builtin_amdgcn_s_setprio(0);

        float mx = -3.0e38f;
        if (domask) {                                // wave-uniform branch
#pragma unroll
            for (int nf = 0; nf < 4; nf++)
#pragma unroll
                for (int r = 0; r < 4; r++) {
                    const int colk = kv0 + nf*16 + lg*4 + r;
                    float v = sacc[nf][r] * SL2E;
                    v = (colk > rowq) ? -3.0e38f : v;
                    sacc[nf][r] = v;
                    mx = fmaxf(mx, v);
                }
        } else {
#pragma unroll
            for (int nf = 0; nf < 4; nf++)
#pragma unroll
                for (int r = 0; r < 4; r++) {
                    const float v = sacc[nf][r] * SL2E;
                    sacc[nf][r] = v;
                    mx = fmaxf(mx, v);
                }
        }
        mx = fmaxf(mx, __shfl_xor(mx, 16));
        mx = fmaxf(mx, __shfl_xor(mx, 32));

        // defer-max: skip rescale while max growth <= 8 (exp2 domain)
        const bool skip = __all(mx <= m + 8.0f);
        const float mn = skip ? m : fmaxf(m, mx);

        float s = 0.0f;
#pragma unroll
        for (int nf = 0; nf < 4; nf++) {
            ushort_t pk[4];
#pragma unroll
            for (int r = 0; r < 4; r++) {
                const float p = exp2f(sacc[nf][r] - mn);
                s += p;
                pk[r] = f2bf(p);
            }
            *(ushort4*)&Ps[w][l15][nf*16 + lg*4] = *(ushort4*)pk;
        }
        s += __shfl_xor(s, 16);
        s += __shfl_xor(s, 32);

        if (skip) {
            l += s;
        } else {
            const float corr = exp2f(m - mn);
            m = mn;
            l = l * corr + s;
            float cf[4];
#pragma unroll
            for (int r = 0; r < 4; r++) cf[r] = __shfl(corr, lg*4 + r);
#pragma unroll
            for (int nf = 0; nf < 4; nf++)
#pragma unroll
                for (int r = 0; r < 4; r++) o[nf][r] *= cf[r];
        }

        __builtin_amdgcn_s_setprio(1);
#pragma unroll
        for (int kc = 0; kc < 2; kc++) {
            bf16x8 pa = *(const bf16x8*)&Ps[w][l15][kc*32 + lg*8];
#pragma unroll
            for (int nf = 0; nf < 4; nf++) {
                bf16x8 bv = *(const bf16x8*)&Vs[buf][nf*16 + l15][(kc*32 + lg*8) ^ swz];
                o[nf] = __builtin_amdgcn_mfma_f32_16x16x32_bf16(pa, bv, o[nf], 0, 0, 0);
            }
        }
        __builtin_amdgcn_s_setprio(0);
    };

    stage(0, 0);
    __syncthreads();
    int buf = 0;

    for (int t = 0; t <= qta; t++) {                 // both strips
        if (t < qtb) stage(buf ^ 1, t + 1);
        compute(buf, t, qa, aqA, mA, lA, oA, t == qta);
        compute(buf, t, qb, aqB, mB, lB, oB, false);
        __syncthreads();
        buf ^= 1;
    }
    for (int t = qta + 1; t <= qtb; t++) {           // strip B only
        if (t < qtb) stage(buf ^ 1, t + 1);
        compute(buf, t, qb, aqB, mB, lB, oB, t == qtb);
        __syncthreads();
        buf ^= 1;
    }

    // epilogue: O /= l (per q-row via shuffle), merge heads
    const int b = bh >> 4, h = bh & 15;
    const float invA = 1.0f / lA, invB = 1.0f / lB;
#pragma unroll
    for (int r = 0; r < 4; r++) {
        const float ia = __shfl(invA, lg*4 + r);
        const float ib = __shfl(invB, lg*4 + r);
        const int rowa = qa + lg*4 + r;
        const int rowb = qb + lg*4 + r;
#pragma unroll
        for (int nf = 0; nf < 4; nf++) {
            Aout[((size_t)(b * S_LEN) + rowa) * DMODEL + h*DHEAD + nf*16 + l15] = f2bf(oA[nf][r] * ia);
            Aout[((size_t)(b * S_LEN) + rowb) * DMODEL + h*DHEAD + nf*16 + l15] = f2bf(oB[nf][r] * ib);
        }
    }
}

extern "C" void kernel_launch(void* const* d_in, const int* in_sizes, int n_in,
                              void* d_out, int out_size, void* d_ws, size_t ws_size,
                              hipStream_t stream) {
    (void)in_sizes; (void)n_in; (void)out_size; (void)ws_size;
    const float* x  = (const float*)d_in[0];
    const float* Wq = (const float*)d_in[2];
    const float* bq = (const float*)d_in[3];
    const float* Wk = (const float*)d_in[4];
    const float* bk = (const float*)d_in[5];
    const float* Wv = (const float*)d_in[6];
    const float* bv = (const float*)d_in[7];
    const float* Wo = (const float*)d_in[8];
    const float* bo = (const float*)d_in[9];

    char* ws = (char*)d_ws;
    ushort_t* xb    = (ushort_t*)(ws);                 // 4096x1024 bf16  (8 MB)
    ushort_t* Wqkvb = (ushort_t*)(ws + (8u  << 20));   // 3072x1024 bf16  (6 MB)
    ushort_t* Wob   = (ushort_t*)(ws + (14u << 20));   // 1024x1024 bf16  (2 MB)
    ushort_t* Qh    = (ushort_t*)(ws + (16u << 20));   // [B][H][S][DH]   (8 MB)
    ushort_t* Kh    = (ushort_t*)(ws + (24u << 20));   // [B][H][S][DH]   (8 MB)
    ushort_t* Vth   = (ushort_t*)(ws + (32u << 20));   // [B][H][DH][S]   (8 MB)
    ushort_t* Ao    = (ushort_t*)(ws + (40u << 20));   // [B][S][D] bf16  (8 MB)

    cast_all<<<2048, 256, 0, stream>>>(x, Wq, Wk, Wv, Wo, xb, 2097152);

    gemm_bt<0, 128><<<dim3(32, 24), 256, 0, stream>>>(xb, Wqkvb, bq, bk, bv,
                                                      Qh, Kh, Vth, 2*S_LEN, 3*DMODEL, DMODEL);

    attn_fwd<<<dim3(16, 2*NHEAD), 256, 0, stream>>>(Qh, Kh, Vth, Ao);

    gemm_bt<2, 64><<<dim3(64, 8), 256, 0, stream>>>(Ao, Wob, bo, nullptr, nullptr,
                                                    d_out, nullptr, nullptr, 2*S_LEN, DMODEL, DMODEL);
}

// Round 7
// 115.180 us; speedup vs baseline: 2.7678x; 1.1090x over previous
//
#include <hip/hip_runtime.h>

#define S_LEN  2048
#define DMODEL 1024
#define NHEAD  16
#define DHEAD  64
#define SCALE_F 0.125f
#define SL2E_F 0.180336880f   // SCALE_F * log2(e)

typedef unsigned short ushort_t;
typedef __attribute__((ext_vector_type(8))) short bf16x8;
typedef __attribute__((ext_vector_type(4))) float f32x4;

typedef __attribute__((address_space(1))) void gv_t;
typedef __attribute__((address_space(3))) void lv_t;

__device__ __forceinline__ ushort_t f2bf(float f) {
    unsigned u = __builtin_bit_cast(unsigned, f);
    unsigned r = (u + 0x7FFFu + ((u >> 16) & 1u)) >> 16;
    return (ushort_t)r;
}

__device__ __forceinline__ unsigned cvtpk_bf16(float a, float b) {
    unsigned r;
    asm("v_cvt_pk_bf16_f32 %0, %1, %2" : "=v"(r) : "v"(a), "v"(b));
    return r;
}

__device__ __forceinline__ void gload16(const ushort_t* g, ushort_t* l) {
    __builtin_amdgcn_global_load_lds((gv_t*)g, (lv_t*)l, 16, 0, 0);
}

// Cast x, Wq, Wk, Wv, Wo (f32) into one contiguous bf16 region.
__global__ void cast_all(const float* __restrict__ x,
                         const float* __restrict__ Wq, const float* __restrict__ Wk,
                         const float* __restrict__ Wv, const float* __restrict__ Wo,
                         ushort_t* __restrict__ dst, int n4) {
    int i = blockIdx.x * blockDim.x + threadIdx.x;
    int stride = gridDim.x * blockDim.x;
    for (int idx = i; idx < n4; idx += stride) {
        const float* src; int off;
        if (idx < 1048576)      { src = x;  off = idx; }
        else if (idx < 1310720) { src = Wq; off = idx - 1048576; }
        else if (idx < 1572864) { src = Wk; off = idx - 1310720; }
        else if (idx < 1835008) { src = Wv; off = idx - 1572864; }
        else                    { src = Wo; off = idx - 1835008; }
        float4 f = ((const float4*)src)[off];
        ushort4 o;
        o.x = f2bf(f.x); o.y = f2bf(f.y); o.z = f2bf(f.z); o.w = f2bf(f.w);
        ((ushort4*)dst)[idx] = o;
    }
}

// C = A @ B^T + bias, 2-phase double-buffered K-loop.
// MODE 0 (BM=128): fused QKV epilogue, N=3072; Q rows additionally scaled by
//   SL2E (folds attention scale+log2e into Q -> attn uses exp2 directly).
// MODE 2 (BM=64): out0 = f32 flat [M][N].
template<int MODE, int BM>
__launch_bounds__(256)
__global__ void gemm_bt(const ushort_t* __restrict__ A, const ushort_t* __restrict__ Bw,
                        const float* __restrict__ b0, const float* __restrict__ b1,
                        const float* __restrict__ b2,
                        void* __restrict__ out0, void* __restrict__ out1, void* __restrict__ out2,
                        int M, int N, int K) {
    constexpr int MF = BM / 32;
    __shared__ ushort_t As[2][BM][32];
    __shared__ ushort_t Bs[2][128][32];
    const int tid  = threadIdx.x;
    const int lane = tid & 63;
    const int w    = tid >> 6;
    const int wr   = w >> 1, wc = w & 1;
    const int m0   = blockIdx.x * BM;
    const int n0   = blockIdx.y * 128;
    const int l15  = lane & 15;
    const int lg   = lane >> 4;
    const int srow = lane >> 2;
    const int scol = (lane & 3) * 8;

    f32x4 acc[MF][4] = {};

    auto stage = [&](int buf, int k0) {
#pragma unroll
        for (int j = 0; j < BM / 64; j++) {
            const int rbase = w * (BM / 4) + j * 16;
            gload16(A + (size_t)(m0 + rbase + srow) * K + k0 + scol, &As[buf][rbase][0]);
        }
#pragma unroll
        for (int j = 0; j < 2; j++) {
            const int rbase = w * 32 + j * 16;
            gload16(Bw + (size_t)(n0 + rbase + srow) * K + k0 + scol, &Bs[buf][rbase][0]);
        }
    };

    stage(0, 0);
    __syncthreads();
    int buf = 0;

    for (int k0 = 0; k0 < K; k0 += 32) {
        if (k0 + 32 < K) stage(buf ^ 1, k0 + 32);
        bf16x8 af[MF], bfr[4];
#pragma unroll
        for (int i = 0; i < MF; i++) af[i]  = *(const bf16x8*)&As[buf][wr*(BM/2) + i*16 + l15][lg*8];
#pragma unroll
        for (int i = 0; i < 4;  i++) bfr[i] = *(const bf16x8*)&Bs[buf][wc*64 + i*16 + l15][lg*8];
#pragma unroll
        for (int mf = 0; mf < MF; mf++)
#pragma unroll
            for (int nf = 0; nf < 4; nf++)
                acc[mf][nf] = __builtin_amdgcn_mfma_f32_16x16x32_bf16(af[mf], bfr[nf], acc[mf][nf], 0, 0, 0);
        __syncthreads();
        buf ^= 1;
    }

#pragma unroll
    for (int mf = 0; mf < MF; mf++) {
#pragma unroll
        for (int nf = 0; nf < 4; nf++) {
            const int col = n0 + wc*64 + nf*16 + l15;
            if constexpr (MODE == 2) {
                const float bv = b0[col];
#pragma unroll
                for (int r = 0; r < 4; r++) {
                    const int row = m0 + wr*(BM/2) + mf*16 + lg*4 + r;
                    ((float*)out0)[(size_t)row * N + col] = acc[mf][nf][r] + bv;
                }
            } else {
                const int mat = col >> 10;
                const int c   = col & 1023;
                const int h   = c >> 6, dh = c & 63;
                const float* bp = (mat == 0) ? b0 : ((mat == 1) ? b1 : b2);
                const float bv = bp[c];
#pragma unroll
                for (int r = 0; r < 4; r++) {
                    const int row = m0 + wr*(BM/2) + mf*16 + lg*4 + r;
                    const int b = row >> 11, s = row & 2047;
                    float v = acc[mf][nf][r] + bv;
                    if (mat == 0) {
                        v *= SL2E_F;   // fold attn scale+log2e into Q
                        ((ushort_t*)out0)[((size_t)(b*NHEAD + h) * S_LEN + s) * DHEAD + dh] = f2bf(v);
                    } else if (mat == 1)
                        ((ushort_t*)out1)[((size_t)(b*NHEAD + h) * S_LEN + s) * DHEAD + dh] = f2bf(v);
                    else
                        ((ushort_t*)out2)[((size_t)(b*NHEAD + h) * DHEAD + dh) * S_LEN + s] = f2bf(v);
                }
            }
        }
    }
}

// Flash attention, causal. One 64-row q-tile per block (16 rows/wave),
// swapped QK^T (q = lane&15, kv = (lane>>4)*4+r), double-buffered K/V
// prefetch, defer-max (THR=8), diagonal-only mask, exp2 domain (Q
// pre-scaled). LDS exactly 40960 B -> 4 blocks/CU. Per-CU balance: the 4
// co-resident blocks (same bh, y=mod-8 class) get qt {2g,31-2g,2g+1,30-2g}.
__launch_bounds__(256, 4)
__global__ void attn_fwd(const ushort_t* __restrict__ Q, const ushort_t* __restrict__ Kh,
                         const ushort_t* __restrict__ Vt, ushort_t* __restrict__ Aout) {
    __shared__ ushort_t Ks[2][64][64];
    __shared__ ushort_t Vs[2][64][64];       // [dh][kv]
    __shared__ ushort_t Ps[4][16][64];       // XOR-swizzled, per-wave
    const int tid  = threadIdx.x;
    const int lane = tid & 63;
    const int w    = tid >> 6;
    const int l15  = lane & 15, lg = lane >> 4;
    const int bh   = blockIdx.x;             // fastest dim: co-resident blocks share bh
    const int y    = blockIdx.y;
    const int kq   = y >> 3, g0 = y & 7;
    const int qt   = (kq == 0) ? 2*g0 : (kq == 1) ? (31 - 2*g0)
                   : (kq == 2) ? (2*g0 + 1) : (30 - 2*g0);

    const size_t qkbase = (size_t)bh * S_LEN * DHEAD;
    const size_t vtbase = (size_t)bh * DHEAD * S_LEN;

    const int rsub  = lane >> 3;                     // staging source swizzle
    const int csw   = ((lane & 7) ^ rsub) * 8;
    const int swz   = (l15 & 7) * 8;                 // K/V read-side XOR (elems)
    const int psxor = (l15 & 7) << 4;                // Ps byte XOR

    const int qw = qt * 64 + w * 16;

    bf16x8 aq[2];
#pragma unroll
    for (int kc = 0; kc < 2; kc++)
        aq[kc] = *(const bf16x8*)(Q + qkbase + (size_t)(qw + l15) * DHEAD + kc*32 + lg*8);

    float m = -3.0e38f, l = 0.0f;
    f32x4 o[4] = {};

    auto stage = [&](int buf, int t) {
        const int kv0 = t * 64;
        const ushort_t* kp = Kh + qkbase + (size_t)kv0 * DHEAD;
        const ushort_t* vp = Vt + vtbase + kv0;
#pragma unroll
        for (int j2 = 0; j2 < 2; j2++) {
            const int j  = w * 2 + j2;
            const int rg = j * 8 + rsub;
            gload16(kp + (size_t)rg * DHEAD + csw, &Ks[buf][j*8][0]);
            gload16(vp + (size_t)rg * S_LEN + csw, &Vs[buf][j*8][0]);
        }
    };

    ushort_t* psw = &Ps[w][0][0];
    char* psrow = (char*)(psw + l15 * 64);

    stage(0, 0);
    __syncthreads();
    int buf = 0;

    for (int t = 0; t <= qt; t++) {
        if (t < qt) stage(buf ^ 1, t + 1);

        // S^T = K Q^T : sacc[nf] row = kv = nf*16+lg*4+r, col = q = l15
        f32x4 sacc[4] = {};
        __builtin_amdgcn_s_setprio(1);
#pragma unroll
        for (int kc = 0; kc < 2; kc++)
#pragma unroll
            for (int nf = 0; nf < 4; nf++) {
                bf16x8 bk = *(const bf16x8*)&Ks[buf][nf*16 + l15][(kc*32 + lg*8) ^ swz];
                sacc[nf] = __builtin_amdgcn_mfma_f32_16x16x32_bf16(bk, aq[kc], sacc[nf], 0, 0, 0);
            }
        __builtin_amdgcn_s_setprio(0);

        if (t == qt) {                               // diagonal tile: causal mask
            const int rowq = qw + l15;
            const int kv0  = t * 64;
#pragma unroll
            for (int nf = 0; nf < 4; nf++)
#pragma unroll
                for (int r = 0; r < 4; r++) {
                    const int colk = kv0 + nf*16 + lg*4 + r;
                    if (colk > rowq) sacc[nf][r] = -3.0e38f;
                }
        }

        // tree max (depth ~4) + cross-lane
        float mnf[4];
#pragma unroll
        for (int nf = 0; nf < 4; nf++)
            mnf[nf] = fmaxf(fmaxf(sacc[nf][0], sacc[nf][1]), fmaxf(sacc[nf][2], sacc[nf][3]));
        float mx = fmaxf(fmaxf(mnf[0], mnf[1]), fmaxf(mnf[2], mnf[3]));
        mx = fmaxf(mx, __shfl_xor(mx, 16));
        mx = fmaxf(mx, __shfl_xor(mx, 32));

        const bool skip = __all(mx <= m + 8.0f);     // defer-max
        const float mn = skip ? m : fmaxf(m, mx);

        float snf[4];
#pragma unroll
        for (int nf = 0; nf < 4; nf++) {
            const float p0 = exp2f(sacc[nf][0] - mn);
            const float p1 = exp2f(sacc[nf][1] - mn);
            const float p2 = exp2f(sacc[nf][2] - mn);
            const float p3 = exp2f(sacc[nf][3] - mn);
            uint2 pk;
            pk.x = cvtpk_bf16(p0, p1);
            pk.y = cvtpk_bf16(p2, p3);
            *(uint2*)(psrow + (((nf*16 + lg*4) * 2) ^ psxor)) = pk;
            snf[nf] = (p0 + p1) + (p2 + p3);
        }
        float s = (snf[0] + snf[1]) + (snf[2] + snf[3]);
        s += __shfl_xor(s, 16);
        s += __shfl_xor(s, 32);

        if (skip) {
            l += s;
        } else {
            const float corr = exp2f(m - mn);
            m = mn;
            l = l * corr + s;
            float cf[4];
#pragma unroll
            for (int r = 0; r < 4; r++) cf[r] = __shfl(corr, lg*4 + r);
#pragma unroll
            for (int nf = 0; nf < 4; nf++)
#pragma unroll
                for (int r = 0; r < 4; r++) o[nf][r] *= cf[r];
        }

        // O += P @ V
        __builtin_amdgcn_s_setprio(1);
#pragma unroll
        for (int kc = 0; kc < 2; kc++) {
            bf16x8 pa = *(const bf16x8*)(psrow + (((kc*32 + lg*8) * 2) ^ psxor));
#pragma unroll
            for (int nf = 0; nf < 4; nf++) {
                bf16x8 bv = *(const bf16x8*)&Vs[buf][nf*16 + l15][(kc*32 + lg*8) ^ swz];
                o[nf] = __builtin_amdgcn_mfma_f32_16x16x32_bf16(pa, bv, o[nf], 0, 0, 0);
            }
        }
        __builtin_amdgcn_s_setprio(0);

        __syncthreads();
        buf ^= 1;
    }

    // epilogue: O /= l (per q-row via shuffle), merge heads
    const int b = bh >> 4, h = bh & 15;
    const float inv = 1.0f / l;
#pragma unroll
    for (int r = 0; r < 4; r++) {
        const float ia = __shfl(inv, lg*4 + r);
        const int rowq = qw + lg*4 + r;
#pragma unroll
        for (int nf = 0; nf < 4; nf++)
            Aout[((size_t)(b * S_LEN) + rowq) * DMODEL + h*DHEAD + nf*16 + l15] = f2bf(o[nf][r] * ia);
    }
}

extern "C" void kernel_launch(void* const* d_in, const int* in_sizes, int n_in,
                              void* d_out, int out_size, void* d_ws, size_t ws_size,
                              hipStream_t stream) {
    (void)in_sizes; (void)n_in; (void)out_size; (void)ws_size;
    const float* x  = (const float*)d_in[0];
    const float* Wq = (const float*)d_in[2];
    const float* bq = (const float*)d_in[3];
    const float* Wk = (const float*)d_in[4];
    const float* bk = (const float*)d_in[5];
    const float* Wv = (const float*)d_in[6];
    const float* bv = (const float*)d_in[7];
    const float* Wo = (const float*)d_in[8];
    const float* bo = (const float*)d_in[9];

    char* ws = (char*)d_ws;
    ushort_t* xb    = (ushort_t*)(ws);                 // 4096x1024 bf16  (8 MB)
    ushort_t* Wqkvb = (ushort_t*)(ws + (8u  << 20));   // 3072x1024 bf16  (6 MB)
    ushort_t* Wob   = (ushort_t*)(ws + (14u << 20));   // 1024x1024 bf16  (2 MB)
    ushort_t* Qh    = (ushort_t*)(ws + (16u << 20));   // [B][H][S][DH]   (8 MB)
    ushort_t* Kh    = (ushort_t*)(ws + (24u << 20));   // [B][H][S][DH]   (8 MB)
    ushort_t* Vth   = (ushort_t*)(ws + (32u << 20));   // [B][H][DH][S]   (8 MB)
    ushort_t* Ao    = (ushort_t*)(ws + (40u << 20));   // [B][S][D] bf16  (8 MB)

    cast_all<<<2048, 256, 0, stream>>>(x, Wq, Wk, Wv, Wo, xb, 2097152);

    gemm_bt<0, 128><<<dim3(32, 24), 256, 0, stream>>>(xb, Wqkvb, bq, bk, bv,
                                                      Qh, Kh, Vth, 2*S_LEN, 3*DMODEL, DMODEL);

    attn_fwd<<<dim3(2*NHEAD, 32), 256, 0, stream>>>(Qh, Kh, Vth, Ao);

    gemm_bt<2, 64><<<dim3(64, 8), 256, 0, stream>>>(Ao, Wob, bo, nullptr, nullptr,
                                                    d_out, nullptr, nullptr, 2*S_LEN, DMODEL, DMODEL);
}